// Round 5
// baseline (64.614 us; speedup 1.0000x reference)
//
#include <hip/hip_runtime.h>
#include <math.h>

// Shapes (hard-coded per reference setup_inputs):
//   b=16, t=128, c=t-1=127, kv_dim=k=64, h=4, q_dim=256
#define Bdim 16
#define Tdim 128
#define Cdim 127
#define Hdim 4
#define QD   256
#define HK   256   // h*k

// ---- DPP cross-lane move (VALU pipe — avoids ds_swizzle on the LDS pipe) ----
#define DPP_XOR1        0xB1   // quad_perm [1,0,3,2]
#define DPP_XOR2        0x4E   // quad_perm [2,3,0,1]
#define DPP_HALF_MIRROR 0x141  // lane ^-> 7-lane within 8 (completes 8-lane reduce)
#define DPP_MIRROR      0x140  // lane ^-> 15-lane within 16 (completes 16-lane reduce)
template<int CTRL>
__device__ __forceinline__ float dpp_movf(float x) {
    return __int_as_float(__builtin_amdgcn_update_dpp(
        0, __float_as_int(x), CTRL, 0xF, 0xF, true));
}

// ---------------------------------------------------------------------------
// K1: M[i, h*64+m] = sum_j Wq[i,h*64+j] * Wk[m,h*64+j]
__global__ __launch_bounds__(256) void precompute_M(
        const float* __restrict__ Wq, const float* __restrict__ Wk,
        float* __restrict__ M) {
    __shared__ float wk_s[64][129];   // padded: 2-way banks (free)
    __shared__ float wq_s[2][128];
    int I = blockIdx.x;               // i-pair
    int H = blockIdx.y;               // head-pair
    int tid = threadIdx.x;

    #pragma unroll
    for (int it = 0; it < 8; ++it) {
        int flat = tid + it * 256;
        int m = flat >> 5, kq = flat & 31;
        float4 v = *(const float4*)(Wk + m * HK + H * 128 + kq * 4);
        wk_s[m][kq*4+0] = v.x; wk_s[m][kq*4+1] = v.y;
        wk_s[m][kq*4+2] = v.z; wk_s[m][kq*4+3] = v.w;
    }
    if (tid < 64) {
        int r = tid >> 5, kq = tid & 31;
        float4 v = *(const float4*)(Wq + (size_t)(I*2+r) * HK + H * 128 + kq * 4);
        wq_s[r][kq*4+0] = v.x; wq_s[r][kq*4+1] = v.y;
        wq_s[r][kq*4+2] = v.z; wq_s[r][kq*4+3] = v.w;
    }
    __syncthreads();

    int r = tid >> 7, hh = (tid >> 6) & 1, m = tid & 63;
    float acc = 0.f;
    #pragma unroll 8
    for (int j = 0; j < 64; ++j)
        acc = fmaf(wq_s[r][hh*64+j], wk_s[m][hh*64+j], acc);
    M[(size_t)(I*2+r) * HK + H * 128 + hh * 64 + m] = acc;
}

// ---------------------------------------------------------------------------
// K2: qk = q_x @ M, K-split into NS partial buffers (summed in attn_main).
template <int NS>
__global__ __launch_bounds__(256) void qk_gemm(
        const float* __restrict__ q_x,
        const float* __restrict__ M,
        float* __restrict__ part) {
    const int KLEN = 256 / NS;
    __shared__ __align__(16) float q_s[16][256 / NS];
    int RB = blockIdx.x;
    int S  = blockIdx.y;
    int tid = threadIdx.x;

    for (int f = tid; f < 16 * KLEN / 4; f += 256) {
        int r = f / (KLEN / 4), kq = f % (KLEN / 4);
        *(float4*)&q_s[r][kq*4] =
            *(const float4*)(q_x + (size_t)(RB*16 + r) * QD + S * KLEN + kq * 4);
    }
    __syncthreads();

    float acc[16];
    #pragma unroll
    for (int r = 0; r < 16; ++r) acc[r] = 0.f;

    for (int kk = 0; kk < KLEN / 4; ++kk) {
        int k = S * KLEN + kk * 4;
        float m0 = M[(size_t)(k+0) * HK + tid];
        float m1 = M[(size_t)(k+1) * HK + tid];
        float m2 = M[(size_t)(k+2) * HK + tid];
        float m3 = M[(size_t)(k+3) * HK + tid];
        #pragma unroll
        for (int r = 0; r < 16; ++r) {
            float4 qv = *(const float4*)&q_s[r][kk*4];
            acc[r] = fmaf(qv.x, m0, fmaf(qv.y, m1, fmaf(qv.z, m2, fmaf(qv.w, m3, acc[r]))));
        }
    }
    float* dst = part + (size_t)S * (Bdim*Tdim*HK) + (size_t)RB * 16 * HK + tid;
    #pragma unroll
    for (int r = 0; r < 16; ++r) dst[r * HK] = acc[r];
}

// ---------------------------------------------------------------------------
// K3: per (b,t): scores -> softmax (DPP) -> wx -> V-proj. 512 thr / 8 waves.
// X row-major float4 chunks, XOR slot swizzle phys = log ^ (c&7), DMA-staged.
__global__ __launch_bounds__(512, 8) void attn_main(
        const float* __restrict__ kv_x,
        const float* __restrict__ qk_p, int nsplit,
        const float* __restrict__ Wv,
        float* __restrict__ out) {
    __shared__ __align__(16) float4 sX4[128 * 16];       // 32 KB; row 127 zeroed
    __shared__ __align__(16) float qk_s[HK];
    __shared__ __align__(16) float e_lds[128 * 5 + 4];   // [c][5]-pad, e per head
    __shared__ __align__(16) float4 wx4[Hdim * 16];      // wx as float4 chunks
    __shared__ float red_max[Hdim][2];
    __shared__ float red_sum[Hdim][2];

    int bt  = blockIdx.x;
    int tid = threadIdx.x;

    // ---- stage X via DMA (linear LDS dest, pre-swizzled global source) ----
    const float4* Xg = (const float4*)(kv_x + (size_t)bt * (Cdim * 64));
    #pragma unroll
    for (int it = 0; it < 4; ++it) {
        int l = tid + it * 512;
        if (l < Cdim * 16) {
            int c = l >> 4, p = l & 15;
            __builtin_amdgcn_global_load_lds(
                (const __attribute__((address_space(1))) void*)(Xg + (c << 4) + (p ^ (c & 7))),
                (__attribute__((address_space(3))) void*)(sX4 + l), 16, 0, 0);
        }
    }
    if (tid >= 256 && tid < 320)
        ((float*)sX4)[Cdim * 64 + (tid - 256)] = 0.f;     // zero pad row 127
    if (tid < 256) {
        float q = 0.f;
        for (int s = 0; s < nsplit; ++s)
            q += qk_p[(size_t)s * (Bdim*Tdim*HK) + (size_t)bt * HK + tid];
        qk_s[tid] = q;
    }
    __syncthreads();                                      // B1

    int h    = tid >> 7;          // head (wave-uniform)
    int c    = tid & 127;         // context row
    int half = (tid >> 6) & 1;
    int lane = tid & 63;
    int sw   = lane & 7;          // == c & 7

    // ---- scores: iterate PHYSICAL slots (immediate LDS offsets);
    //      xor moved to the qk multicast side (8 groups x 8 lanes, no conflict)
    float s;
    {
        const float4* qrow = (const float4*)(qk_s + h * 64);
        const float4* xrow = sX4 + c * 16;
        float acc = 0.f;
        #pragma unroll
        for (int p = 0; p < 16; ++p) {
            float4 x4 = xrow[p];                 // linear b128, struct-min banks
            float4 qv = qrow[p ^ sw];            // logical chunk matches x4
            acc = fmaf(qv.x, x4.x, fmaf(qv.y, x4.y, fmaf(qv.z, x4.z, fmaf(qv.w, x4.w, acc))));
        }
        s = (c < Cdim) ? acc * 0.125f : -INFINITY;   // 1/sqrt(64); row 127 pad
    }

    // ---- softmax max: DPP within 16 lanes, shfl only for 16/32 ----
    float mx = s;
    mx = fmaxf(mx, dpp_movf<DPP_XOR1>(mx));
    mx = fmaxf(mx, dpp_movf<DPP_XOR2>(mx));
    mx = fmaxf(mx, dpp_movf<DPP_HALF_MIRROR>(mx));
    mx = fmaxf(mx, dpp_movf<DPP_MIRROR>(mx));
    mx = fmaxf(mx, __shfl_xor(mx, 16, 64));
    mx = fmaxf(mx, __shfl_xor(mx, 32, 64));
    if (lane == 0) red_max[h][half] = mx;
    __syncthreads();                                      // B2
    float gm = fmaxf(red_max[h][0], red_max[h][1]);
    float e = __expf(s - gm);                             // c==127 -> 0
    e_lds[c * 5 + h] = e;                                 // 2-way write (free)
    float sm = e;
    sm += dpp_movf<DPP_XOR1>(sm);
    sm += dpp_movf<DPP_XOR2>(sm);
    sm += dpp_movf<DPP_HALF_MIRROR>(sm);
    sm += dpp_movf<DPP_MIRROR>(sm);
    sm += __shfl_xor(sm, 16, 64);
    sm += __shfl_xor(sm, 32, 64);
    if (lane == 0) red_sum[h][half] = sm;
    __syncthreads();                                      // B3 (e_lds visible)

    // ---- wx[h][jc] = sum_c e[h,c] * X[c, chunk jc]; thread=(h,jc,csub) ----
    // c = csub + 8m: c&7 == csub, so swizzled chunk index (jc^csub) is
    // CONSTANT per thread; the m-loop is pure immediate-offset ds_reads.
    {
        int jc = (tid >> 3) & 15;
        int cs = tid & 7;
        const float4* xbase = sX4 + cs * 16 + (jc ^ cs);
        const float* ebase  = e_lds + cs * 5 + h;
        float4 a = {0.f, 0.f, 0.f, 0.f};
        #pragma unroll
        for (int m = 0; m < 16; ++m) {
            float4 x4 = xbase[m * 128];          // row cs+8m, offset:m*2048
            float ev  = ebase[m * 40];           // conflict-free 8-group bcast
            a.x = fmaf(ev, x4.x, a.x);
            a.y = fmaf(ev, x4.y, a.y);
            a.z = fmaf(ev, x4.z, a.z);
            a.w = fmaf(ev, x4.w, a.w);
        }
        // reduce over csub (lane bits 0..2) entirely on the VALU via DPP
        a.x += dpp_movf<DPP_XOR1>(a.x); a.y += dpp_movf<DPP_XOR1>(a.y);
        a.z += dpp_movf<DPP_XOR1>(a.z); a.w += dpp_movf<DPP_XOR1>(a.w);
        a.x += dpp_movf<DPP_XOR2>(a.x); a.y += dpp_movf<DPP_XOR2>(a.y);
        a.z += dpp_movf<DPP_XOR2>(a.z); a.w += dpp_movf<DPP_XOR2>(a.w);
        a.x += dpp_movf<DPP_HALF_MIRROR>(a.x); a.y += dpp_movf<DPP_HALF_MIRROR>(a.y);
        a.z += dpp_movf<DPP_HALF_MIRROR>(a.z); a.w += dpp_movf<DPP_HALF_MIRROR>(a.w);
        if (cs == 0) wx4[h * 16 + jc] = a;       // 8 lanes, distinct banks
    }
    __syncthreads();                                      // B4

    // ---- out[h,k] = inv * sum_j wx[h,j] * Wv[j, h*64+k]; tid<256 ----
    if (tid < 256) {
        int hh = tid >> 6, k = tid & 63;
        float inv = 1.f / (red_sum[hh][0] + red_sum[hh][1]);
        const float* wvcol = Wv + hh * 64 + k;
        float acc = 0.f;
        #pragma unroll 4
        for (int jc = 0; jc < 16; ++jc) {
            float4 w4 = wx4[hh * 16 + jc];       // b128 broadcast (was 8x b32)
            acc = fmaf(w4.x, wvcol[(size_t)(jc*4+0) * HK], acc);
            acc = fmaf(w4.y, wvcol[(size_t)(jc*4+1) * HK], acc);
            acc = fmaf(w4.z, wvcol[(size_t)(jc*4+2) * HK], acc);
            acc = fmaf(w4.w, wvcol[(size_t)(jc*4+3) * HK], acc);
        }
        out[(size_t)bt * HK + tid] = acc * inv;
    }
}

extern "C" void kernel_launch(void* const* d_in, const int* in_sizes, int n_in,
                              void* d_out, int out_size, void* d_ws, size_t ws_size,
                              hipStream_t stream) {
    const float* q_x  = (const float*)d_in[0];   // [16,128,256]
    const float* kv_x = (const float*)d_in[1];   // [16,128,127,64]
    const float* Wq   = (const float*)d_in[2];   // [256,256]
    const float* Wk   = (const float*)d_in[3];   // [64,256]
    const float* Wv   = (const float*)d_in[4];   // [64,256]
    float* out = (float*)d_out;                  // [16,128,256] f32

    float* M     = (float*)d_ws;                 // 256*256 floats
    float* parts = M + 256 * 256;                // NS * 2048*256 floats

    size_t need4 = (size_t)(256*256 + 4 * Bdim*Tdim*HK) * sizeof(float);
    int nsplit = (ws_size >= need4) ? 4 : 1;

    precompute_M<<<dim3(128, 2), 256, 0, stream>>>(Wq, Wk, M);
    if (nsplit == 4)
        qk_gemm<4><<<dim3(128, 4), 256, 0, stream>>>(q_x, M, parts);
    else
        qk_gemm<1><<<dim3(128, 1), 256, 0, stream>>>(q_x, M, parts);
    attn_main<<<Bdim * Tdim, 512, 0, stream>>>(kv_x, parts, nsplit, Wv, out);
}

// Round 6
// 42.048 us; speedup vs baseline: 1.5367x; 1.5367x over previous
//
#include <hip/hip_runtime.h>
#include <math.h>

// Shapes (hard-coded per reference setup_inputs):
//   b=16, t=128, c=t-1=127, kv_dim=k=64, h=4, q_dim=256
#define Bdim 16
#define Tdim 128
#define Cdim 127
#define Hdim 4
#define QD   256
#define HK   256   // h*k

// ---- DPP cross-lane move (VALU pipe — avoids ds_swizzle on the LDS pipe) ----
#define DPP_XOR1        0xB1   // quad_perm [1,0,3,2]
#define DPP_XOR2        0x4E   // quad_perm [2,3,0,1]
#define DPP_HALF_MIRROR 0x141  // mirror within 8 lanes
#define DPP_MIRROR      0x140  // mirror within 16 lanes
template<int CTRL>
__device__ __forceinline__ float dpp_movf(float x) {
    return __int_as_float(__builtin_amdgcn_update_dpp(
        0, __float_as_int(x), CTRL, 0xF, 0xF, true));
}

// ---------------------------------------------------------------------------
// K1: M[i, h*64+m] = sum_j Wq[i,h*64+j] * Wk[m,h*64+j]
__global__ __launch_bounds__(256) void precompute_M(
        const float* __restrict__ Wq, const float* __restrict__ Wk,
        float* __restrict__ M) {
    __shared__ float wk_s[64][129];   // padded: 2-way banks (free)
    __shared__ float wq_s[2][128];
    int I = blockIdx.x;               // i-pair
    int H = blockIdx.y;               // head-pair
    int tid = threadIdx.x;

    #pragma unroll
    for (int it = 0; it < 8; ++it) {
        int flat = tid + it * 256;
        int m = flat >> 5, kq = flat & 31;
        float4 v = *(const float4*)(Wk + m * HK + H * 128 + kq * 4);
        wk_s[m][kq*4+0] = v.x; wk_s[m][kq*4+1] = v.y;
        wk_s[m][kq*4+2] = v.z; wk_s[m][kq*4+3] = v.w;
    }
    if (tid < 64) {
        int r = tid >> 5, kq = tid & 31;
        float4 v = *(const float4*)(Wq + (size_t)(I*2+r) * HK + H * 128 + kq * 4);
        wq_s[r][kq*4+0] = v.x; wq_s[r][kq*4+1] = v.y;
        wq_s[r][kq*4+2] = v.z; wq_s[r][kq*4+3] = v.w;
    }
    __syncthreads();

    int r = tid >> 7, hh = (tid >> 6) & 1, m = tid & 63;
    float acc = 0.f;
    #pragma unroll 8
    for (int j = 0; j < 64; ++j)
        acc = fmaf(wq_s[r][hh*64+j], wk_s[m][hh*64+j], acc);
    M[(size_t)(I*2+r) * HK + H * 128 + hh * 64 + m] = acc;
}

// ---------------------------------------------------------------------------
// K2: qk = q_x @ M, K-split into NS partial buffers (summed in attn_main).
template <int NS>
__global__ __launch_bounds__(256) void qk_gemm(
        const float* __restrict__ q_x,
        const float* __restrict__ M,
        float* __restrict__ part) {
    const int KLEN = 256 / NS;
    __shared__ __align__(16) float q_s[16][256 / NS];
    int RB = blockIdx.x;
    int S  = blockIdx.y;
    int tid = threadIdx.x;

    for (int f = tid; f < 16 * KLEN / 4; f += 256) {
        int r = f / (KLEN / 4), kq = f % (KLEN / 4);
        *(float4*)&q_s[r][kq*4] =
            *(const float4*)(q_x + (size_t)(RB*16 + r) * QD + S * KLEN + kq * 4);
    }
    __syncthreads();

    float acc[16];
    #pragma unroll
    for (int r = 0; r < 16; ++r) acc[r] = 0.f;

    for (int kk = 0; kk < KLEN / 4; ++kk) {
        int k = S * KLEN + kk * 4;
        float m0 = M[(size_t)(k+0) * HK + tid];
        float m1 = M[(size_t)(k+1) * HK + tid];
        float m2 = M[(size_t)(k+2) * HK + tid];
        float m3 = M[(size_t)(k+3) * HK + tid];
        #pragma unroll
        for (int r = 0; r < 16; ++r) {
            float4 qv = *(const float4*)&q_s[r][kk*4];
            acc[r] = fmaf(qv.x, m0, fmaf(qv.y, m1, fmaf(qv.z, m2, fmaf(qv.w, m3, acc[r]))));
        }
    }
    float* dst = part + (size_t)S * (Bdim*Tdim*HK) + (size_t)RB * 16 * HK + tid;
    #pragma unroll
    for (int r = 0; r < 16; ++r) dst[r * HK] = acc[r];
}

// ---------------------------------------------------------------------------
// K3: per (b,t): scores -> softmax (DPP) -> wx -> V-proj. 512 thr / 8 waves.
// X row-major float4 chunks, XOR slot swizzle phys = log ^ (c&7), DMA-staged.
__global__ __launch_bounds__(512, 8) void attn_main(
        const float* __restrict__ kv_x,
        const float* __restrict__ qk_p, int nsplit,
        const float* __restrict__ Wv,
        float* __restrict__ out) {
    __shared__ __align__(16) float4 sX4[128 * 16];       // 32 KB; row 127 zeroed
    __shared__ __align__(16) float qk_s[HK];
    __shared__ __align__(16) float e_lds[128 * 5 + 4];   // [c][5]-pad, e per head
    __shared__ __align__(16) float4 wx4[Hdim * 16];      // wx as float4 chunks
    __shared__ float red_max[Hdim][2];
    __shared__ float red_sum[Hdim][2];

    int bt  = blockIdx.x;
    int tid = threadIdx.x;

    // ---- stage X via DMA (linear LDS dest, pre-swizzled global source) ----
    const float4* Xg = (const float4*)(kv_x + (size_t)bt * (Cdim * 64));
    #pragma unroll
    for (int it = 0; it < 4; ++it) {
        int l = tid + it * 512;
        if (l < Cdim * 16) {
            int c = l >> 4, p = l & 15;
            __builtin_amdgcn_global_load_lds(
                (const __attribute__((address_space(1))) void*)(Xg + (c << 4) + (p ^ (c & 7))),
                (__attribute__((address_space(3))) void*)(sX4 + l), 16, 0, 0);
        }
    }
    if (tid >= 256 && tid < 320)
        ((float*)sX4)[Cdim * 64 + (tid - 256)] = 0.f;     // zero pad row 127
    if (tid < 256) {
        float q = 0.f;
        for (int s = 0; s < nsplit; ++s)
            q += qk_p[(size_t)s * (Bdim*Tdim*HK) + (size_t)bt * HK + tid];
        qk_s[tid] = q;
    }
    __syncthreads();                                      // B1

    int h    = tid >> 7;          // head (wave-uniform)
    int c    = tid & 127;         // context row
    int half = (tid >> 6) & 1;
    int lane = tid & 63;
    int sw   = c & 7;

    // ---- scores: X read swizzled (8 addrs x 8 bank-groups = struct-min),
    //      qk read is a same-address broadcast per iteration ----
    float s;
    {
        const float4* qrow = (const float4*)(qk_s + h * 64);
        const float4* xrow = sX4 + c * 16;
        float acc = 0.f;
        #pragma unroll
        for (int p = 0; p < 16; ++p) {
            float4 qv = qrow[p];                 // broadcast (1 addr/wave)
            float4 x4 = xrow[p ^ sw];            // 8 bank-groups, 8 rows each
            acc = fmaf(qv.x, x4.x, fmaf(qv.y, x4.y, fmaf(qv.z, x4.z, fmaf(qv.w, x4.w, acc))));
        }
        s = (c < Cdim) ? acc * 0.125f : -INFINITY;   // 1/sqrt(64); row 127 pad
    }

    // ---- softmax max: DPP within 16 lanes, shfl only for 16/32 ----
    float mx = s;
    mx = fmaxf(mx, dpp_movf<DPP_XOR1>(mx));
    mx = fmaxf(mx, dpp_movf<DPP_XOR2>(mx));
    mx = fmaxf(mx, dpp_movf<DPP_HALF_MIRROR>(mx));
    mx = fmaxf(mx, dpp_movf<DPP_MIRROR>(mx));
    mx = fmaxf(mx, __shfl_xor(mx, 16, 64));
    mx = fmaxf(mx, __shfl_xor(mx, 32, 64));
    if (lane == 0) red_max[h][half] = mx;
    __syncthreads();                                      // B2
    float gm = fmaxf(red_max[h][0], red_max[h][1]);
    float e = __expf(s - gm);                             // c==127 -> 0
    e_lds[c * 5 + h] = e;                                 // spread banks (5c+h)
    float sm = e;
    sm += dpp_movf<DPP_XOR1>(sm);
    sm += dpp_movf<DPP_XOR2>(sm);
    sm += dpp_movf<DPP_HALF_MIRROR>(sm);
    sm += dpp_movf<DPP_MIRROR>(sm);
    sm += __shfl_xor(sm, 16, 64);
    sm += __shfl_xor(sm, 32, 64);
    if (lane == 0) red_sum[h][half] = sm;
    __syncthreads();                                      // B3 (e_lds visible)

    // ---- wx[h][jc] = sum_c e[h,c] * X[c, chunk jc]; thread=(h,jc,csub) ----
    // c = csub + 8m: c&7 == csub, so swizzled chunk index (jc^csub) is
    // CONSTANT per thread; the m-loop is pure immediate-offset ds_reads.
    {
        int jc = (tid >> 3) & 15;
        int cs = tid & 7;
        const float4* xbase = sX4 + cs * 16 + (jc ^ cs);
        const float* ebase  = e_lds + cs * 5 + h;
        float4 a = {0.f, 0.f, 0.f, 0.f};
        #pragma unroll
        for (int m = 0; m < 16; ++m) {
            float4 x4 = xbase[m * 128];          // row cs+8m, offset:m*2048
            float ev  = ebase[m * 40];           // 8 addrs on 8 distinct banks
            a.x = fmaf(ev, x4.x, a.x);
            a.y = fmaf(ev, x4.y, a.y);
            a.z = fmaf(ev, x4.z, a.z);
            a.w = fmaf(ev, x4.w, a.w);
        }
        // reduce over csub (lane bits 0..2) entirely on the VALU via DPP
        a.x += dpp_movf<DPP_XOR1>(a.x); a.y += dpp_movf<DPP_XOR1>(a.y);
        a.z += dpp_movf<DPP_XOR1>(a.z); a.w += dpp_movf<DPP_XOR1>(a.w);
        a.x += dpp_movf<DPP_XOR2>(a.x); a.y += dpp_movf<DPP_XOR2>(a.y);
        a.z += dpp_movf<DPP_XOR2>(a.z); a.w += dpp_movf<DPP_XOR2>(a.w);
        a.x += dpp_movf<DPP_HALF_MIRROR>(a.x); a.y += dpp_movf<DPP_HALF_MIRROR>(a.y);
        a.z += dpp_movf<DPP_HALF_MIRROR>(a.z); a.w += dpp_movf<DPP_HALF_MIRROR>(a.w);
        if (cs == 0) wx4[h * 16 + jc] = a;       // 8 lanes -> all 32 banks once
    }
    __syncthreads();                                      // B4

    // ---- out[h,k] = inv * sum_j wx[h,j] * Wv[j, h*64+k]; tid<256 ----
    if (tid < 256) {
        int hh = tid >> 6, k = tid & 63;
        float inv = 1.f / (red_sum[hh][0] + red_sum[hh][1]);
        const float* wvcol = Wv + hh * 64 + k;
        float acc = 0.f;
        #pragma unroll 4
        for (int jc = 0; jc < 16; ++jc) {
            float4 w4 = wx4[hh * 16 + jc];       // b128 broadcast
            acc = fmaf(w4.x, wvcol[(size_t)(jc*4+0) * HK], acc);
            acc = fmaf(w4.y, wvcol[(size_t)(jc*4+1) * HK], acc);
            acc = fmaf(w4.z, wvcol[(size_t)(jc*4+2) * HK], acc);
            acc = fmaf(w4.w, wvcol[(size_t)(jc*4+3) * HK], acc);
        }
        out[(size_t)bt * HK + tid] = acc * inv;
    }
}

extern "C" void kernel_launch(void* const* d_in, const int* in_sizes, int n_in,
                              void* d_out, int out_size, void* d_ws, size_t ws_size,
                              hipStream_t stream) {
    const float* q_x  = (const float*)d_in[0];   // [16,128,256]
    const float* kv_x = (const float*)d_in[1];   // [16,128,127,64]
    const float* Wq   = (const float*)d_in[2];   // [256,256]
    const float* Wk   = (const float*)d_in[3];   // [64,256]
    const float* Wv   = (const float*)d_in[4];   // [64,256]
    float* out = (float*)d_out;                  // [16,128,256] f32

    float* M     = (float*)d_ws;                 // 256*256 floats
    float* parts = M + 256 * 256;                // NS * 2048*256 floats

    size_t need4 = (size_t)(256*256 + 4 * Bdim*Tdim*HK) * sizeof(float);
    int nsplit = (ws_size >= need4) ? 4 : 1;

    precompute_M<<<dim3(128, 2), 256, 0, stream>>>(Wq, Wk, M);
    if (nsplit == 4)
        qk_gemm<4><<<dim3(128, 4), 256, 0, stream>>>(q_x, M, parts);
    else
        qk_gemm<1><<<dim3(128, 1), 256, 0, stream>>>(q_x, M, parts);
    attn_main<<<Bdim * Tdim, 512, 0, stream>>>(kv_x, parts, nsplit, Wv, out);
}